// Round 1
// baseline (268.387 us; speedup 1.0000x reference)
//
#include <hip/hip_runtime.h>

// SpinorBilinears: K0 = psi.psi, T[c][d] = psi^T gamma_c gamma_d psi = u[c].v[d]
// K1 = 0.5(T - T^T), K2 = 0.5(T + T^T)
// Tokens = B*N = 524288, S=4, C=8. Outputs f32 concat: K0 | K1 | K2.

#define TPB 128           // threads == tokens per block
#define LDS_STRIDE 68     // 64 + 4 pad: keeps b128 LDS ops bank-balanced

__device__ __forceinline__ float dot4(float4 a, float4 b) {
    return a.x * b.x + a.y * b.y + a.z * b.z + a.w * b.w;
}

__global__ __launch_bounds__(TPB) void spinor_bilinears_kernel(
    const float* __restrict__ psi,
    const float* __restrict__ gamma,
    float* __restrict__ out,
    long long n_tokens) {
    __shared__ float ldsT[TPB * LDS_STRIDE];

    const int tid = threadIdx.x;
    const long long t_glob = (long long)blockIdx.x * TPB + tid;

    float* K0 = out;
    float* K1 = out + n_tokens;
    float* K2 = out + n_tokens + n_tokens * 64;

    // ---- Phase 1: per-token compute ----
    const float4 p = ((const float4*)psi)[t_glob];

    // K0: coalesced dword store (consecutive lanes -> consecutive tokens)
    K0[t_glob] = dot4(p, p);

    // u[c][k] = sum_i psi_i * gamma[c][i][k]   (psi^T gamma_c)
    // v[c][k] = sum_j gamma[c][k][j] * psi_j   (gamma_c psi)
    float4 u[8], v[8];
    const float4* g4 = (const float4*)gamma;  // g4[c*4 + i] = gamma[c][i][0..3]
#pragma unroll
    for (int c = 0; c < 8; ++c) {
        const float4 g0 = g4[c * 4 + 0];
        const float4 g1 = g4[c * 4 + 1];
        const float4 g2 = g4[c * 4 + 2];
        const float4 g3 = g4[c * 4 + 3];
        float4 uc;
        uc.x = p.x * g0.x + p.y * g1.x + p.z * g2.x + p.w * g3.x;
        uc.y = p.x * g0.y + p.y * g1.y + p.z * g2.y + p.w * g3.y;
        uc.z = p.x * g0.z + p.y * g1.z + p.z * g2.z + p.w * g3.z;
        uc.w = p.x * g0.w + p.y * g1.w + p.z * g2.w + p.w * g3.w;
        u[c] = uc;
        float4 vc;
        vc.x = dot4(g0, p);
        vc.y = dot4(g1, p);
        vc.z = dot4(g2, p);
        vc.w = dot4(g3, p);
        v[c] = vc;
    }

    // T[c][d] = dot(u[c], v[d]) -> LDS row for this token (b128 writes,
    // bank-balanced because stride 68 spreads lanes over all 8 bank-quads)
    float* row = &ldsT[tid * LDS_STRIDE];
#pragma unroll
    for (int c = 0; c < 8; ++c) {
        float4 t0, t1;
        t0.x = dot4(u[c], v[0]);
        t0.y = dot4(u[c], v[1]);
        t0.z = dot4(u[c], v[2]);
        t0.w = dot4(u[c], v[3]);
        t1.x = dot4(u[c], v[4]);
        t1.y = dot4(u[c], v[5]);
        t1.z = dot4(u[c], v[6]);
        t1.w = dot4(u[c], v[7]);
        ((float4*)(row + c * 8))[0] = t0;
        ((float4*)(row + c * 8))[1] = t1;
    }

    __syncthreads();

    // ---- Phase 2: coalesced block-wide streaming of K1/K2 ----
    // Block's K1 region: TPB*64 = 8192 floats = 2048 float4; 128 threads x 16 iters.
    const long long blk_base = (long long)blockIdx.x * (TPB * 64);
    float4* K1v = (float4*)(K1 + blk_base);
    float4* K2v = (float4*)(K2 + blk_base);

    const int cd0 = (tid & 15) * 4;       // first cd of this lane's float4
    const int c = cd0 >> 3;
    const int d0 = cd0 & 7;               // 0 or 4

#pragma unroll
    for (int it = 0; it < 16; ++it) {
        const int t = it * 8 + (tid >> 4);              // local token
        const float* trow = &ldsT[t * LDS_STRIDE];
        const float4 tcd = *(const float4*)(trow + cd0);  // T[c][d0..d0+3]
        const float td0 = trow[(d0 + 0) * 8 + c];         // T[d'][c]
        const float td1 = trow[(d0 + 1) * 8 + c];
        const float td2 = trow[(d0 + 2) * 8 + c];
        const float td3 = trow[(d0 + 3) * 8 + c];

        float4 k1v, k2v;
        k1v.x = 0.5f * (tcd.x - td0);  k2v.x = 0.5f * (tcd.x + td0);
        k1v.y = 0.5f * (tcd.y - td1);  k2v.y = 0.5f * (tcd.y + td1);
        k1v.z = 0.5f * (tcd.z - td2);  k2v.z = 0.5f * (tcd.z + td2);
        k1v.w = 0.5f * (tcd.w - td3);  k2v.w = 0.5f * (tcd.w + td3);

        K1v[it * 128 + tid] = k1v;     // consecutive lanes -> consecutive 16B
        K2v[it * 128 + tid] = k2v;
    }
}

extern "C" void kernel_launch(void* const* d_in, const int* in_sizes, int n_in,
                              void* d_out, int out_size, void* d_ws, size_t ws_size,
                              hipStream_t stream) {
    const float* psi = (const float*)d_in[0];
    const float* gamma = (const float*)d_in[1];
    float* out = (float*)d_out;

    const long long n_tokens = (long long)in_sizes[0] / 4;  // B*N = 524288
    const int blocks = (int)(n_tokens / TPB);               // 4096

    spinor_bilinears_kernel<<<blocks, TPB, 0, stream>>>(psi, gamma, out, n_tokens);
}